// Round 5
// baseline (1105.978 us; speedup 1.0000x reference)
//
#include <hip/hip_runtime.h>
#include <hip/hip_bf16.h>

// MemoryAttention on MI355X: bf16-resident pipeline, split-K flash attention.
// B=8, S=512, M=4096, D=256, H=8, dh=32, DFF=2048, L=2.
// (Resubmission of R3 — previous bench failed on GPU acquisition, no data.)

#define NTOK 4096
#define NMEM 32768
#define DMODEL 256
#define DFF_ 2048

typedef __attribute__((ext_vector_type(8))) short bf16x8;
typedef __attribute__((ext_vector_type(4))) short bf16x4;
typedef __attribute__((ext_vector_type(4))) float f32x4;
typedef unsigned short u16;

__device__ __forceinline__ u16 f2bf(float f) {
  return __builtin_bit_cast(u16, __float2bfloat16(f));
}
__device__ __forceinline__ float bf2f(u16 u) {
  unsigned int x = ((unsigned int)u) << 16;
  return __builtin_bit_cast(float, x);
}
__device__ __forceinline__ void gload16(const u16* g, u16* l) {
  __builtin_amdgcn_global_load_lds(
      (const __attribute__((address_space(1))) unsigned int*)g,
      (__attribute__((address_space(3))) unsigned int*)l, 16, 0, 0);
}

// ---------------- x = a + s*b (f32) ----------------
__global__ __launch_bounds__(256) void add_kernel(const float* __restrict__ a,
                                                  const float* __restrict__ b,
                                                  float s, float* __restrict__ o, int n4) {
  int i = blockIdx.x * blockDim.x + threadIdx.x;
  int st = gridDim.x * blockDim.x;
  for (; i < n4; i += st) {
    float4 va = ((const float4*)a)[i];
    float4 vb = ((const float4*)b)[i];
    float4 r;
    r.x = va.x + s * vb.x; r.y = va.y + s * vb.y;
    r.z = va.z + s * vb.z; r.w = va.w + s * vb.w;
    ((float4*)o)[i] = r;
  }
}

// ---------------- memk = bf16(mem+pos), memv = bf16(mem) ----------------
__global__ __launch_bounds__(256) void memprep_kernel(const float* __restrict__ mem,
                                                      const float* __restrict__ pos,
                                                      u16* __restrict__ memk,
                                                      u16* __restrict__ memv, int n8) {
  int i = blockIdx.x * blockDim.x + threadIdx.x;
  int st = gridDim.x * blockDim.x;
  for (; i < n8; i += st) {
    float4 m0 = ((const float4*)mem)[i * 2], m1 = ((const float4*)mem)[i * 2 + 1];
    float4 p0 = ((const float4*)pos)[i * 2], p1 = ((const float4*)pos)[i * 2 + 1];
    bf16x8 v, k;
    v[0] = (short)f2bf(m0.x); v[1] = (short)f2bf(m0.y);
    v[2] = (short)f2bf(m0.z); v[3] = (short)f2bf(m0.w);
    v[4] = (short)f2bf(m1.x); v[5] = (short)f2bf(m1.y);
    v[6] = (short)f2bf(m1.z); v[7] = (short)f2bf(m1.w);
    k[0] = (short)f2bf(m0.x + p0.x); k[1] = (short)f2bf(m0.y + p0.y);
    k[2] = (short)f2bf(m0.z + p0.z); k[3] = (short)f2bf(m0.w + p0.w);
    k[4] = (short)f2bf(m1.x + p1.x); k[5] = (short)f2bf(m1.y + p1.y);
    k[6] = (short)f2bf(m1.z + p1.z); k[7] = (short)f2bf(m1.w + p1.w);
    *(bf16x8*)(memv + (size_t)i * 8) = v;
    *(bf16x8*)(memk + (size_t)i * 8) = k;
  }
}

// ---------------- weight cast f32 -> bf16 (8 segments) ----------------
struct WArgs { const float* src[8]; int off[8]; int n[8]; };
__global__ __launch_bounds__(256) void wcast_kernel(WArgs a, u16* __restrict__ dst) {
  int st = gridDim.x * blockDim.x;
  for (int j = 0; j < 8; ++j) {
    const float* s = a.src[j];
    u16* d = dst + a.off[j];
    int n8 = a.n[j] >> 3;
    for (int i = blockIdx.x * blockDim.x + threadIdx.x; i < n8; i += st) {
      float4 x0 = ((const float4*)s)[i * 2], x1 = ((const float4*)s)[i * 2 + 1];
      bf16x8 o;
      o[0] = (short)f2bf(x0.x); o[1] = (short)f2bf(x0.y);
      o[2] = (short)f2bf(x0.z); o[3] = (short)f2bf(x0.w);
      o[4] = (short)f2bf(x1.x); o[5] = (short)f2bf(x1.y);
      o[6] = (short)f2bf(x1.z); o[7] = (short)f2bf(x1.w);
      *(bf16x8*)(d + (size_t)i * 8) = o;
    }
  }
}

// ---------------- layernorm D=256; OBF: bf16 or f32 out ----------------
template <int OBF>
__global__ __launch_bounds__(256) void ln_kernel(const float* __restrict__ x,
                                                 const float* __restrict__ g,
                                                 const float* __restrict__ b,
                                                 void* __restrict__ y) {
  int row = blockIdx.x, t = threadIdx.x;
  float v = x[(size_t)row * 256 + t];
  float s = v;
#pragma unroll
  for (int off = 32; off; off >>= 1) s += __shfl_xor(s, off);
  __shared__ float r1[4], r2[4];
  int wid = t >> 6, lane = t & 63;
  if (!lane) r1[wid] = s;
  __syncthreads();
  float mean = (r1[0] + r1[1] + r1[2] + r1[3]) * (1.f / 256.f);
  float d = v - mean;
  float q = d * d;
#pragma unroll
  for (int off = 32; off; off >>= 1) q += __shfl_xor(q, off);
  if (!lane) r2[wid] = q;
  __syncthreads();
  float var = (r2[0] + r2[1] + r2[2] + r2[3]) * (1.f / 256.f);
  float r = d * rsqrtf(var + 1e-5f) * g[t] + b[t];
  if constexpr (OBF) ((u16*)y)[(size_t)row * 256 + t] = f2bf(r);
  else ((float*)y)[(size_t)row * 256 + t] = r;
}

// ---------------- enhanced = x + s*emb[b][d] -> bf16 ----------------
__global__ __launch_bounds__(256) void enh_kernel(const float* __restrict__ x,
                                                  const float* __restrict__ emb,
                                                  const float* __restrict__ sp,
                                                  u16* __restrict__ o, int n4) {
  float s = sp[0];
  int i = blockIdx.x * blockDim.x + threadIdx.x;
  int st = gridDim.x * blockDim.x;
  for (; i < n4; i += st) {
    int base = i << 2;
    int b = base >> 17;
    int d = base & 255;
    float4 vx = ((const float4*)x)[i];
    float4 ve = *(const float4*)&emb[b * 256 + d];
    ushort4 r;
    r.x = f2bf(vx.x + s * ve.x); r.y = f2bf(vx.y + s * ve.y);
    r.z = f2bf(vx.z + s * ve.z); r.w = f2bf(vx.w + s * ve.w);
    *(ushort4*)(o + base) = r;
  }
}

// ---------------- V transpose: out[h][d][tok] = in[tok][col0+h*32+d] ----------------
__global__ __launch_bounds__(256) void transpose_v(const u16* __restrict__ in, int ld,
                                                   int col0, u16* __restrict__ out,
                                                   int ntok) {
  int h = blockIdx.y;
  int tok0 = blockIdx.x * 64;
  int tid = threadIdx.x;
  int d = tid >> 3, g = tid & 7;
  const u16* src = in + col0 + h * 32 + d;
  bf16x8 o;
#pragma unroll
  for (int j = 0; j < 8; ++j) o[j] = (short)src[(size_t)(tok0 + g * 8 + j) * ld];
  *(bf16x8*)(out + (size_t)(h * 32 + d) * ntok + tok0 + g * 8) = o;
}

// ---------------- GEMM 128x128 (4 waves), bf16 A/W, global_load_lds ----------------
template <int CBF>
__global__ __launch_bounds__(256) void gemm128_kernel(const u16* __restrict__ A,
                                                      const u16* __restrict__ W,
                                                      const float* __restrict__ bias,
                                                      const float* __restrict__ resid,
                                                      void* __restrict__ C,
                                                      int N, int M, int K, int relu) {
  __shared__ u16 As[128 * 32];
  __shared__ u16 Ws[128 * 32];
  int tid = threadIdx.x, lane = tid & 63, w = tid >> 6;
  int l15 = lane & 15, lg = lane >> 4;
  int n0 = blockIdx.y * 128, m0 = blockIdx.x * 128;
  int wr = (w >> 1) * 64, wc = (w & 1) * 64;
  const u16* Ag = A + (size_t)(n0 + w * 32 + (lane >> 2)) * K + (lane & 3) * 8;
  const u16* Wg = W + (size_t)(m0 + w * 32 + (lane >> 2)) * K + (lane & 3) * 8;
  u16* Al0 = &As[w * 1024]; u16* Al1 = &As[w * 1024 + 512];
  u16* Wl0 = &Ws[w * 1024]; u16* Wl1 = &Ws[w * 1024 + 512];
  f32x4 acc[4][4] = {};
  for (int k0 = 0; k0 < K; k0 += 32) {
    __syncthreads();
    gload16(Ag + k0, Al0);
    gload16(Ag + (size_t)16 * K + k0, Al1);
    gload16(Wg + k0, Wl0);
    gload16(Wg + (size_t)16 * K + k0, Wl1);
    __syncthreads();
    bf16x8 af[4], wf[4];
#pragma unroll
    for (int f = 0; f < 4; ++f) {
      af[f] = *(const bf16x8*)&As[(wr + f * 16 + l15) * 32 + lg * 8];
      wf[f] = *(const bf16x8*)&Ws[(wc + f * 16 + l15) * 32 + lg * 8];
    }
#pragma unroll
    for (int fm = 0; fm < 4; ++fm)
#pragma unroll
      for (int fn = 0; fn < 4; ++fn)
        acc[fm][fn] = __builtin_amdgcn_mfma_f32_16x16x32_bf16(af[fm], wf[fn], acc[fm][fn], 0, 0, 0);
  }
#pragma unroll
  for (int fm = 0; fm < 4; ++fm)
#pragma unroll
    for (int fn = 0; fn < 4; ++fn)
#pragma unroll
      for (int r = 0; r < 4; ++r) {
        int row = n0 + wr + fm * 16 + lg * 4 + r;
        int col = m0 + wc + fn * 16 + l15;
        float v = acc[fm][fn][r] + bias[col];
        if (relu) v = fmaxf(v, 0.f);
        if constexpr (CBF) {
          ((u16*)C)[(size_t)row * M + col] = f2bf(v);
        } else {
          if (resid) v += resid[(size_t)row * M + col];
          ((float*)C)[(size_t)row * M + col] = v;
        }
      }
}

// ---------------- GEMM 64x64 (1 wave) ----------------
template <int CBF>
__global__ __launch_bounds__(64) void gemm64_kernel(const u16* __restrict__ A,
                                                    const u16* __restrict__ W,
                                                    const float* __restrict__ bias,
                                                    const float* __restrict__ resid,
                                                    void* __restrict__ C,
                                                    int N, int M, int K, int relu) {
  __shared__ u16 As[64 * 32];
  __shared__ u16 Ws[64 * 32];
  int lane = threadIdx.x;
  int l15 = lane & 15, lg = lane >> 4;
  int n0 = blockIdx.y * 64, m0 = blockIdx.x * 64;
  const u16* Ag = A + (size_t)(n0 + (lane >> 2)) * K + (lane & 3) * 8;
  const u16* Wg = W + (size_t)(m0 + (lane >> 2)) * K + (lane & 3) * 8;
  f32x4 acc[4][4] = {};
  for (int k0 = 0; k0 < K; k0 += 32) {
    __syncthreads();
#pragma unroll
    for (int i = 0; i < 4; ++i) {
      gload16(Ag + (size_t)(i * 16) * K + k0, &As[i * 512]);
      gload16(Wg + (size_t)(i * 16) * K + k0, &Ws[i * 512]);
    }
    __syncthreads();
    bf16x8 af[4], wf[4];
#pragma unroll
    for (int f = 0; f < 4; ++f) {
      af[f] = *(const bf16x8*)&As[(f * 16 + l15) * 32 + lg * 8];
      wf[f] = *(const bf16x8*)&Ws[(f * 16 + l15) * 32 + lg * 8];
    }
#pragma unroll
    for (int fm = 0; fm < 4; ++fm)
#pragma unroll
      for (int fn = 0; fn < 4; ++fn)
        acc[fm][fn] = __builtin_amdgcn_mfma_f32_16x16x32_bf16(af[fm], wf[fn], acc[fm][fn], 0, 0, 0);
  }
#pragma unroll
  for (int fm = 0; fm < 4; ++fm)
#pragma unroll
    for (int fn = 0; fn < 4; ++fn)
#pragma unroll
      for (int r = 0; r < 4; ++r) {
        int row = n0 + fm * 16 + lg * 4 + r;
        int col = m0 + fn * 16 + l15;
        float v = acc[fm][fn][r] + bias[col];
        if (relu) v = fmaxf(v, 0.f);
        if constexpr (CBF) {
          ((u16*)C)[(size_t)row * M + col] = f2bf(v);
        } else {
          if (resid) v += resid[(size_t)row * M + col];
          ((float*)C)[(size_t)row * M + col] = v;
        }
      }
}

// ---------------- split-K flash attention (partials) ----------------
// Grid = ntile*ksplit (ntile = nqt*H*B). Block: 4 waves, 64 queries.
// Swapped QK^T in log2 domain (scale includes log2e); 2-deep A/B pipelined
// chunk loop (static reg indices); deferred o-rescale; writes unnormalized
// bf16 o-partials + f32 m/l to ws; combine kernel merges splits.
__global__ __launch_bounds__(256) void attn_kernel(
    const u16* __restrict__ Q, const u16* __restrict__ Kp,
    const u16* __restrict__ Vt,
    int ldq, int ldk, int ldvt, int Sk, int nqt, int ksplit,
    int qB, int kB, int vB, const int* __restrict__ img, float scale,
    u16* __restrict__ opart, float* __restrict__ mlpart) {
  int tid = threadIdx.x, lane = tid & 63, w = tid >> 6;
  int l15 = lane & 15, lg = lane >> 4;
  int u_ = blockIdx.x;
  int wid = (u_ & 7) * (gridDim.x >> 3) + (u_ >> 3);  // XCD remap (grid%8==0)
  int ntile = gridDim.x / ksplit;
  int split = wid / ntile;          // split-outer: consecutive wid share K-seg
  int tile = wid % ntile;
  int qt = tile % nqt, bh = tile / nqt, h = bh & 7, b = bh >> 3;
  int q_tile = qt * 64 + w * 16;

  const u16* Qb = Q + (size_t)b * qB + h * 32;
  const u16* Kb = Kp + (size_t)b * kB + h * 32;
  const u16* Vb = Vt + (size_t)(h * 32) * ldvt + b * vB;

  // admissible chunk range (contiguous)
  int c_lo = 0, c_cnt = Sk >> 6;
  if (img) {
    int qimg = img[(qt * 64) >> 9];
    unsigned long long adm = 0;
#pragma unroll
    for (int j = 0; j < 8; ++j)
      if (img[j] == qimg) adm |= (0xFFull << (8 * j));
    c_lo = __ffsll((long long)adm) - 1;
    c_cnt = __popcll(adm);
  }
  int cbeg = c_lo + (c_cnt * split) / ksplit;
  int cend = c_lo + (c_cnt * (split + 1)) / ksplit;

  bf16x8 qf;
  {
    bf16x8 qr = *(const bf16x8*)(Qb + (size_t)(q_tile + l15) * ldq + lg * 8);
#pragma unroll
    for (int i = 0; i < 8; ++i) qf[i] = (short)f2bf(bf2f((u16)qr[i]) * scale);
  }

  float m_ = -1e30f, l_ = 0.f;
  f32x4 o0 = {}, o1 = {};

  bf16x8 kfA[4], kfB[4];
  bf16x4 vA0[4], vA1[4], vB0[4], vB1[4];

  auto kvload = [&](bf16x8 (&KF)[4], bf16x4 (&V0)[4], bf16x4 (&V1)[4], int cc) {
    const u16* kbase = Kb + (size_t)(cc << 6) * ldk;
#pragma unroll
    for (int t = 0; t < 4; ++t)
      KF[t] = *(const bf16x8*)(kbase + (size_t)(t * 16 + l15) * ldk + lg * 8);
    const u16* vr0 = Vb + (size_t)l15 * ldvt + (cc << 6);
    const u16* vr1 = Vb + (size_t)(16 + l15) * ldvt + (cc << 6);
#pragma unroll
    for (int t = 0; t < 4; ++t) {
      V0[t] = *(const bf16x4*)(vr0 + t * 16 + lg * 4);
      V1[t] = *(const bf16x4*)(vr1 + t * 16 + lg * 4);
    }
  };

  auto chunk = [&](bf16x8 (&KF)[4], bf16x4 (&V0)[4], bf16x4 (&V1)[4]) {
    f32x4 z = {};
    f32x4 st[4];
#pragma unroll
    for (int t = 0; t < 4; ++t)
      st[t] = __builtin_amdgcn_mfma_f32_16x16x32_bf16(KF[t], qf, z, 0, 0, 0);
    float a0 = fmaxf(fmaxf(st[0][0], st[0][1]), fmaxf(st[0][2], st[0][3]));
    float a1 = fmaxf(fmaxf(st[1][0], st[1][1]), fmaxf(st[1][2], st[1][3]));
    float a2 = fmaxf(fmaxf(st[2][0], st[2][1]), fmaxf(st[2][2], st[2][3]));
    float a3 = fmaxf(fmaxf(st[3][0], st[3][1]), fmaxf(st[3][2], st[3][3]));
    float cm = fmaxf(fmaxf(a0, a1), fmaxf(a2, a3));
    cm = fmaxf(cm, __shfl_xor(cm, 16));
    cm = fmaxf(cm, __shfl_xor(cm, 32));
    bool need = __any(cm > m_);
    float mn = fmaxf(m_, cm);
    float p[4][4];
    float r4[4];
#pragma unroll
    for (int t = 0; t < 4; ++t) {
      p[t][0] = __builtin_exp2f(st[t][0] - mn);
      p[t][1] = __builtin_exp2f(st[t][1] - mn);
      p[t][2] = __builtin_exp2f(st[t][2] - mn);
      p[t][3] = __builtin_exp2f(st[t][3] - mn);
      r4[t] = (p[t][0] + p[t][1]) + (p[t][2] + p[t][3]);
    }
    float rs = (r4[0] + r4[1]) + (r4[2] + r4[3]);
    rs += __shfl_xor(rs, 16);
    rs += __shfl_xor(rs, 32);
    if (need) {
      float sf = __builtin_exp2f(m_ - mn);
      m_ = mn;
#pragma unroll
      for (int r = 0; r < 4; ++r) {
        float s4 = __shfl(sf, lg * 4 + r);
        o0[r] *= s4;
        o1[r] *= s4;
      }
      l_ = l_ * sf + rs;
    } else {
      l_ += rs;
    }
#pragma unroll
    for (int t = 0; t < 4; ++t) {
      bf16x4 pa;
      pa[0] = (short)f2bf(p[t][0]); pa[1] = (short)f2bf(p[t][1]);
      pa[2] = (short)f2bf(p[t][2]); pa[3] = (short)f2bf(p[t][3]);
      o0 = __builtin_amdgcn_mfma_f32_16x16x16bf16_1k(pa, V0[t], o0, 0, 0, 0);
      o1 = __builtin_amdgcn_mfma_f32_16x16x16bf16_1k(pa, V1[t], o1, 0, 0, 0);
    }
  };

  kvload(kfA, vA0, vA1, cbeg);
  int c = cbeg;
  for (; c + 1 < cend; c += 2) {
    kvload(kfB, vB0, vB1, c + 1);
    chunk(kfA, vA0, vA1);
    if (c + 2 < cend) kvload(kfA, vA0, vA1, c + 2);
    chunk(kfB, vB0, vB1);
  }
  if (c < cend) chunk(kfA, vA0, vA1);

  // ---- write partials (canonical index: tile*ksplit + split) ----
  int blk = tile * ksplit + split;
  u16* op = opart + (size_t)blk * 2048;
#pragma unroll
  for (int r = 0; r < 4; ++r) {
    int ql = w * 16 + lg * 4 + r;
    op[ql * 32 + l15] = f2bf(o0[r]);
    op[ql * 32 + 16 + l15] = f2bf(o1[r]);
  }
  if (lg == 0) {
    float* ml = mlpart + (size_t)blk * 128;
    ml[w * 16 + l15] = m_;
    ml[64 + w * 16 + l15] = l_;
  }
}

// ---------------- combine partials -> bf16 output [tok][256] ----------------
template <int KS>
__global__ __launch_bounds__(256) void attn_combine(const u16* __restrict__ opart,
                                                    const float* __restrict__ mlpart,
                                                    u16* __restrict__ O,
                                                    int nqt, int SqB) {
  int tile = blockIdx.x;
  int qt = tile % nqt, bh = tile / nqt, h = bh & 7, b = bh >> 3;
  int t = threadIdx.x;
  int q = t >> 2, d0 = (t & 3) * 8;
  float m[KS], l[KS];
#pragma unroll
  for (int s = 0; s < KS; ++s) {
    const float* ml = mlpart + (size_t)(tile * KS + s) * 128;
    m[s] = ml[q];
    l[s] = ml[64 + q];
  }
  float M = m[0];
#pragma unroll
  for (int s = 1; s < KS; ++s) M = fmaxf(M, m[s]);
  float wgt[KS];
  float L = 0.f;
#pragma unroll
  for (int s = 0; s < KS; ++s) {
    wgt[s] = __builtin_exp2f(m[s] - M);
    L += l[s] * wgt[s];
  }
  float inv = 1.f / L;
  float acc[8] = {};
#pragma unroll
  for (int s = 0; s < KS; ++s) {
    const u16* op = opart + (size_t)(tile * KS + s) * 2048 + q * 32 + d0;
    bf16x8 v = *(const bf16x8*)op;
#pragma unroll
    for (int j = 0; j < 8; ++j) acc[j] += bf2f((u16)v[j]) * wgt[s];
  }
  u16* out = O + ((size_t)(b * SqB + qt * 64 + q)) * 256 + h * 32 + d0;
  ushort4 w0, w1;
  w0.x = f2bf(acc[0] * inv); w0.y = f2bf(acc[1] * inv);
  w0.z = f2bf(acc[2] * inv); w0.w = f2bf(acc[3] * inv);
  w1.x = f2bf(acc[4] * inv); w1.y = f2bf(acc[5] * inv);
  w1.z = f2bf(acc[6] * inv); w1.w = f2bf(acc[7] * inv);
  *(ushort4*)out = w0;
  *(ushort4*)(out + 4) = w1;
}

// ---------------- orchestration ----------------
extern "C" void kernel_launch(void* const* d_in, const int* in_sizes, int n_in,
                              void* d_out, int out_size, void* d_ws, size_t ws_size,
                              hipStream_t stream) {
  const float* curr       = (const float*)d_in[0];
  const float* memory     = (const float*)d_in[1];
  const float* curr_pos   = (const float*)d_in[2];
  const float* memory_pos = (const float*)d_in[3];
  const int*   img_ids    = (const int*)d_in[4];
  const float* sa_w_in  = (const float*)d_in[5];
  const float* sa_b_in  = (const float*)d_in[6];
  const float* sa_w_out = (const float*)d_in[7];
  const float* sa_b_out = (const float*)d_in[8];
  const float* co_w_in  = (const float*)d_in[9];
  const float* co_b_in  = (const float*)d_in[10];
  const float* co_w_out = (const float*)d_in[11];
  const float* co_b_out = (const float*)d_in[12];
  const float* ca_w_in  = (const float*)d_in[13];
  const float* ca_b_in  = (const float*)d_in[14];
  const float* ca_w_out = (const float*)d_in[15];
  const float* ca_b_out = (const float*)d_in[16];
  const float* obj_emb  = (const float*)d_in[17];
  const float* obj_scale= (const float*)d_in[18];
  const float* n1_g = (const float*)d_in[19];
  const float* n1_b = (const float*)d_in[20];
  const float* n2_g = (const float*)d_in[21];
  const float* n2_b = (const float*)d_in[22];
  const float* n3_g = (const float*)d_in[23];
  const float* n3_b = (const float*)d_in[24];
  const float* w1 = (const float*)d_in[25];
  const float* b1 = (const float*)d_in[26];
  const float* w2 = (const float*)d_in[27];
  const float* b2 = (const float*)d_in[28];
  const float* norm_g = (const float*)d_in[29];
  const float* norm_b = (const float*)d_in[30];
  float* out = (float*)d_out;

  char* p = (char*)d_ws;
  float* x    = (float*)p;  p += (size_t)NTOK * DMODEL * 4;
  u16* t2b    = (u16*)p;    p += (size_t)NTOK * DMODEL * 2;
  u16* qkvb   = (u16*)p;    p += (size_t)NTOK * 768 * 2;
  u16* qproj  = (u16*)p;    p += (size_t)NTOK * DMODEL * 2;
  u16* attb   = (u16*)p;    p += (size_t)NTOK * DMODEL * 2;
  u16* memk   = (u16*)p;    p += (size_t)NMEM * DMODEL * 2;
  u16* memv   = (u16*)p;    p += (size_t)NMEM * DMODEL * 2;
  u16* kbufb  = (u16*)p;    p += (size_t)NMEM * DMODEL * 2;
  u16* vbufb  = (u16*)p;    p += (size_t)NMEM * DMODEL * 2;  // hbuf alias in MLP
  u16* vtca   = (u16*)p;    p += (size_t)NMEM * DMODEL * 2;
  u16* vtx    = (u16*)p;    p += (size_t)NTOK * DMODEL * 2;
  u16* wbf    = (u16*)p;    p += (size_t)3670016 * 2;
  u16* hbufb  = vbufb;
  // partials: SA/CO alias kbufb (dead there); CA alias vbufb (dead post-transpose)
  u16* opart1   = kbufb;                          // <= 2048 blk * 4KB = 8MB
  float* mlp1   = (float*)(kbufb + 2048 * 2048);  // 1MB
  u16* opart2   = vbufb;
  float* mlp2   = (float*)(vbufb + 2048 * 2048);

  const float scale = 0.17677669529663687f * 1.4426950408889634f;  // /sqrt(32) * log2(e)

  WArgs wa;
  const float* sp[8] = {sa_w_in, sa_w_out, co_w_in, co_w_out, ca_w_in, ca_w_out, w1, w2};
  int sz[8] = {393216, 131072, 393216, 131072, 393216, 131072, 1048576, 1048576};
  {
    int off = 0;
    for (int j = 0; j < 8; ++j) { wa.src[j] = sp[j]; wa.off[j] = off; wa.n[j] = sz[j]; off += sz[j]; }
  }
  const int O_SA_IN = 0, O_SA_OUT = 393216, O_CO_IN = 524288, O_CO_OUT = 917504;
  const int O_CA_IN = 1048576, O_CA_OUT = 1441792, O_W1 = 1572864, O_W2 = 2621440;

  wcast_kernel<<<512, 256, 0, stream>>>(wa, wbf);
  memprep_kernel<<<2048, 256, 0, stream>>>(memory, memory_pos, memk, memv, NMEM * DMODEL / 8);
  add_kernel<<<1024, 256, 0, stream>>>(curr, curr_pos, 0.1f, x, NTOK * DMODEL / 4);

  for (int l = 0; l < 2; ++l) {
    const u16* w_sa_in  = wbf + O_SA_IN  + l * 196608;
    const u16* w_sa_out = wbf + O_SA_OUT + l * 65536;
    const u16* w_co_in  = wbf + O_CO_IN  + l * 196608;
    const u16* w_co_out = wbf + O_CO_OUT + l * 65536;
    const u16* w_ca_in  = wbf + O_CA_IN  + l * 196608;
    const u16* w_ca_out = wbf + O_CA_OUT + l * 65536;
    const u16* w_1      = wbf + O_W1     + l * 524288;
    const u16* w_2      = wbf + O_W2     + l * 524288;

    // ---- self-attention (ntile=512, ksplit=2) ----
    ln_kernel<1><<<NTOK, 256, 0, stream>>>(x, n1_g + l * 256, n1_b + l * 256, t2b);
    gemm64_kernel<1><<<dim3(12, 64), 64, 0, stream>>>(t2b, w_sa_in, sa_b_in + l * 768,
                                                      nullptr, qkvb, NTOK, 768, 256, 0);
    transpose_v<<<dim3(64, 8), 256, 0, stream>>>(qkvb, 768, 512, vtx, NTOK);
    attn_kernel<<<1024, 256, 0, stream>>>(qkvb, qkvb + 256, vtx,
                                          768, 768, 4096, 512, 8, 2,
                                          512 * 768, 512 * 768, 512, nullptr, scale,
                                          opart1, mlp1);
    attn_combine<2><<<512, 256, 0, stream>>>(opart1, mlp1, attb, 8, 512);
    gemm64_kernel<0><<<dim3(4, 64), 64, 0, stream>>>(attb, w_sa_out, sa_b_out + l * 256,
                                                     x, x, NTOK, 256, 256, 0);
    // ---- cross-object attention (ntile=512, ksplit=4, image mask) ----
    enh_kernel<<<1024, 256, 0, stream>>>(x, obj_emb + l * 8 * 256, obj_scale + l,
                                         t2b, NTOK * DMODEL / 4);
    gemm64_kernel<1><<<dim3(12, 64), 64, 0, stream>>>(t2b, w_co_in, co_b_in + l * 768,
                                                      nullptr, qkvb, NTOK, 768, 256, 0);
    transpose_v<<<dim3(64, 8), 256, 0, stream>>>(qkvb, 768, 512, vtx, NTOK);
    attn_kernel<<<2048, 256, 0, stream>>>(qkvb, qkvb + 256, vtx,
                                          768, 768, 4096, 4096, 64, 4,
                                          0, 0, 0, img_ids, scale,
                                          opart1, mlp1);
    attn_combine<4><<<512, 256, 0, stream>>>(opart1, mlp1, attb, 64, 4096);
    gemm64_kernel<0><<<dim3(4, 64), 64, 0, stream>>>(attb, w_co_out, co_b_out + l * 256,
                                                     x, x, NTOK, 256, 256, 0);
    // ---- cross-attention to memory (ntile=512, ksplit=4) ----
    ln_kernel<1><<<NTOK, 256, 0, stream>>>(x, n2_g + l * 256, n2_b + l * 256, t2b);
    gemm64_kernel<1><<<dim3(4, 64), 64, 0, stream>>>(t2b, w_ca_in, ca_b_in + l * 768,
                                                     nullptr, qproj, NTOK, 256, 256, 0);
    gemm128_kernel<1><<<dim3(2, 256), 256, 0, stream>>>(memk, w_ca_in + 65536,
                                                        ca_b_in + l * 768 + 256, nullptr,
                                                        kbufb, NMEM, 256, 256, 0);
    gemm128_kernel<1><<<dim3(2, 256), 256, 0, stream>>>(memv, w_ca_in + 131072,
                                                        ca_b_in + l * 768 + 512, nullptr,
                                                        vbufb, NMEM, 256, 256, 0);
    transpose_v<<<dim3(512, 8), 256, 0, stream>>>(vbufb, 256, 0, vtca, NMEM);
    attn_kernel<<<2048, 256, 0, stream>>>(qproj, kbufb, vtca,
                                          256, 256, 32768, 4096, 8, 4,
                                          512 * 256, 4096 * 256, 4096, nullptr, scale,
                                          opart2, mlp2);
    attn_combine<4><<<512, 256, 0, stream>>>(opart2, mlp2, attb, 8, 512);
    gemm64_kernel<0><<<dim3(4, 64), 64, 0, stream>>>(attb, w_ca_out, ca_b_out + l * 256,
                                                     x, x, NTOK, 256, 256, 0);
    // ---- MLP ----
    ln_kernel<1><<<NTOK, 256, 0, stream>>>(x, n3_g + l * 256, n3_b + l * 256, t2b);
    gemm128_kernel<1><<<dim3(16, 32), 256, 0, stream>>>(t2b, w_1, b1 + l * 2048, nullptr,
                                                        hbufb, NTOK, 2048, 256, 1);
    gemm64_kernel<0><<<dim3(4, 64), 64, 0, stream>>>(hbufb, w_2, b2 + l * 256,
                                                     x, x, NTOK, 256, 2048, 0);
  }
  ln_kernel<0><<<NTOK, 256, 0, stream>>>(x, norm_g, norm_b, out);
}

// Round 6
// 806.637 us; speedup vs baseline: 1.3711x; 1.3711x over previous
//
#include <hip/hip_runtime.h>
#include <hip/hip_bf16.h>

// MemoryAttention on MI355X: bf16 pipeline, LDS-staged split-K flash attention.
// B=8, S=512, M=4096, D=256, H=8, dh=32, DFF=2048, L=2.

#define NTOK 4096
#define NMEM 32768
#define DMODEL 256
#define DFF_ 2048

typedef __attribute__((ext_vector_type(8))) short bf16x8;
typedef __attribute__((ext_vector_type(4))) short bf16x4;
typedef __attribute__((ext_vector_type(4))) float f32x4;
typedef unsigned short u16;

__device__ __forceinline__ u16 f2bf(float f) {
  return __builtin_bit_cast(u16, __float2bfloat16(f));
}
__device__ __forceinline__ float bf2f(u16 u) {
  unsigned int x = ((unsigned int)u) << 16;
  return __builtin_bit_cast(float, x);
}
__device__ __forceinline__ void gload16(const u16* g, u16* l) {
  __builtin_amdgcn_global_load_lds(
      (const __attribute__((address_space(1))) unsigned int*)g,
      (__attribute__((address_space(3))) unsigned int*)l, 16, 0, 0);
}

// ---------------- x = a + s*b (f32) ----------------
__global__ __launch_bounds__(256) void add_kernel(const float* __restrict__ a,
                                                  const float* __restrict__ b,
                                                  float s, float* __restrict__ o, int n4) {
  int i = blockIdx.x * blockDim.x + threadIdx.x;
  int st = gridDim.x * blockDim.x;
  for (; i < n4; i += st) {
    float4 va = ((const float4*)a)[i];
    float4 vb = ((const float4*)b)[i];
    float4 r;
    r.x = va.x + s * vb.x; r.y = va.y + s * vb.y;
    r.z = va.z + s * vb.z; r.w = va.w + s * vb.w;
    ((float4*)o)[i] = r;
  }
}

// ---------------- memk = bf16(mem+pos), memv = bf16(mem) ----------------
__global__ __launch_bounds__(256) void memprep_kernel(const float* __restrict__ mem,
                                                      const float* __restrict__ pos,
                                                      u16* __restrict__ memk,
                                                      u16* __restrict__ memv, int n8) {
  int i = blockIdx.x * blockDim.x + threadIdx.x;
  int st = gridDim.x * blockDim.x;
  for (; i < n8; i += st) {
    float4 m0 = ((const float4*)mem)[i * 2], m1 = ((const float4*)mem)[i * 2 + 1];
    float4 p0 = ((const float4*)pos)[i * 2], p1 = ((const float4*)pos)[i * 2 + 1];
    bf16x8 v, k;
    v[0] = (short)f2bf(m0.x); v[1] = (short)f2bf(m0.y);
    v[2] = (short)f2bf(m0.z); v[3] = (short)f2bf(m0.w);
    v[4] = (short)f2bf(m1.x); v[5] = (short)f2bf(m1.y);
    v[6] = (short)f2bf(m1.z); v[7] = (short)f2bf(m1.w);
    k[0] = (short)f2bf(m0.x + p0.x); k[1] = (short)f2bf(m0.y + p0.y);
    k[2] = (short)f2bf(m0.z + p0.z); k[3] = (short)f2bf(m0.w + p0.w);
    k[4] = (short)f2bf(m1.x + p1.x); k[5] = (short)f2bf(m1.y + p1.y);
    k[6] = (short)f2bf(m1.z + p1.z); k[7] = (short)f2bf(m1.w + p1.w);
    *(bf16x8*)(memv + (size_t)i * 8) = v;
    *(bf16x8*)(memk + (size_t)i * 8) = k;
  }
}

// ---------------- weight cast f32 -> bf16 (8 segments) ----------------
struct WArgs { const float* src[8]; int off[8]; int n[8]; };
__global__ __launch_bounds__(256) void wcast_kernel(WArgs a, u16* __restrict__ dst) {
  int st = gridDim.x * blockDim.x;
  for (int j = 0; j < 8; ++j) {
    const float* s = a.src[j];
    u16* d = dst + a.off[j];
    int n8 = a.n[j] >> 3;
    for (int i = blockIdx.x * blockDim.x + threadIdx.x; i < n8; i += st) {
      float4 x0 = ((const float4*)s)[i * 2], x1 = ((const float4*)s)[i * 2 + 1];
      bf16x8 o;
      o[0] = (short)f2bf(x0.x); o[1] = (short)f2bf(x0.y);
      o[2] = (short)f2bf(x0.z); o[3] = (short)f2bf(x0.w);
      o[4] = (short)f2bf(x1.x); o[5] = (short)f2bf(x1.y);
      o[6] = (short)f2bf(x1.z); o[7] = (short)f2bf(x1.w);
      *(bf16x8*)(d + (size_t)i * 8) = o;
    }
  }
}

// ---------------- layernorm D=256; OBF: bf16 or f32 out ----------------
template <int OBF>
__global__ __launch_bounds__(256) void ln_kernel(const float* __restrict__ x,
                                                 const float* __restrict__ g,
                                                 const float* __restrict__ b,
                                                 void* __restrict__ y) {
  int row = blockIdx.x, t = threadIdx.x;
  float v = x[(size_t)row * 256 + t];
  float s = v;
#pragma unroll
  for (int off = 32; off; off >>= 1) s += __shfl_xor(s, off);
  __shared__ float r1[4], r2[4];
  int wid = t >> 6, lane = t & 63;
  if (!lane) r1[wid] = s;
  __syncthreads();
  float mean = (r1[0] + r1[1] + r1[2] + r1[3]) * (1.f / 256.f);
  float d = v - mean;
  float q = d * d;
#pragma unroll
  for (int off = 32; off; off >>= 1) q += __shfl_xor(q, off);
  if (!lane) r2[wid] = q;
  __syncthreads();
  float var = (r2[0] + r2[1] + r2[2] + r2[3]) * (1.f / 256.f);
  float r = d * rsqrtf(var + 1e-5f) * g[t] + b[t];
  if constexpr (OBF) ((u16*)y)[(size_t)row * 256 + t] = f2bf(r);
  else ((float*)y)[(size_t)row * 256 + t] = r;
}

// ---------------- enhanced = x + s*emb[b][d] -> bf16 ----------------
__global__ __launch_bounds__(256) void enh_kernel(const float* __restrict__ x,
                                                  const float* __restrict__ emb,
                                                  const float* __restrict__ sp,
                                                  u16* __restrict__ o, int n4) {
  float s = sp[0];
  int i = blockIdx.x * blockDim.x + threadIdx.x;
  int st = gridDim.x * blockDim.x;
  for (; i < n4; i += st) {
    int base = i << 2;
    int b = base >> 17;
    int d = base & 255;
    float4 vx = ((const float4*)x)[i];
    float4 ve = *(const float4*)&emb[b * 256 + d];
    ushort4 r;
    r.x = f2bf(vx.x + s * ve.x); r.y = f2bf(vx.y + s * ve.y);
    r.z = f2bf(vx.z + s * ve.z); r.w = f2bf(vx.w + s * ve.w);
    *(ushort4*)(o + base) = r;
  }
}

// ---------------- V transpose: out[h][d][tok] = in[tok][col0+h*32+d] ----------------
__global__ __launch_bounds__(256) void transpose_v(const u16* __restrict__ in, int ld,
                                                   int col0, u16* __restrict__ out,
                                                   int ntok) {
  int h = blockIdx.y;
  int tok0 = blockIdx.x * 64;
  int tid = threadIdx.x;
  int d = tid >> 3, g = tid & 7;
  const u16* src = in + col0 + h * 32 + d;
  bf16x8 o;
#pragma unroll
  for (int j = 0; j < 8; ++j) o[j] = (short)src[(size_t)(tok0 + g * 8 + j) * ld];
  *(bf16x8*)(out + (size_t)(h * 32 + d) * ntok + tok0 + g * 8) = o;
}

// ---------------- GEMM 128x128 (4 waves), bf16 A/W, global_load_lds ----------------
template <int CBF>
__global__ __launch_bounds__(256) void gemm128_kernel(const u16* __restrict__ A,
                                                      const u16* __restrict__ W,
                                                      const float* __restrict__ bias,
                                                      const float* __restrict__ resid,
                                                      void* __restrict__ C,
                                                      int N, int M, int K, int relu) {
  __shared__ u16 As[128 * 32];
  __shared__ u16 Ws[128 * 32];
  int tid = threadIdx.x, lane = tid & 63, w = tid >> 6;
  int l15 = lane & 15, lg = lane >> 4;
  int n0 = blockIdx.y * 128, m0 = blockIdx.x * 128;
  int wr = (w >> 1) * 64, wc = (w & 1) * 64;
  const u16* Ag = A + (size_t)(n0 + w * 32 + (lane >> 2)) * K + (lane & 3) * 8;
  const u16* Wg = W + (size_t)(m0 + w * 32 + (lane >> 2)) * K + (lane & 3) * 8;
  u16* Al0 = &As[w * 1024]; u16* Al1 = &As[w * 1024 + 512];
  u16* Wl0 = &Ws[w * 1024]; u16* Wl1 = &Ws[w * 1024 + 512];
  f32x4 acc[4][4] = {};
  for (int k0 = 0; k0 < K; k0 += 32) {
    __syncthreads();
    gload16(Ag + k0, Al0);
    gload16(Ag + (size_t)16 * K + k0, Al1);
    gload16(Wg + k0, Wl0);
    gload16(Wg + (size_t)16 * K + k0, Wl1);
    __syncthreads();
    bf16x8 af[4], wf[4];
#pragma unroll
    for (int f = 0; f < 4; ++f) {
      af[f] = *(const bf16x8*)&As[(wr + f * 16 + l15) * 32 + lg * 8];
      wf[f] = *(const bf16x8*)&Ws[(wc + f * 16 + l15) * 32 + lg * 8];
    }
#pragma unroll
    for (int fm = 0; fm < 4; ++fm)
#pragma unroll
      for (int fn = 0; fn < 4; ++fn)
        acc[fm][fn] = __builtin_amdgcn_mfma_f32_16x16x32_bf16(af[fm], wf[fn], acc[fm][fn], 0, 0, 0);
  }
#pragma unroll
  for (int fm = 0; fm < 4; ++fm)
#pragma unroll
    for (int fn = 0; fn < 4; ++fn)
#pragma unroll
      for (int r = 0; r < 4; ++r) {
        int row = n0 + wr + fm * 16 + lg * 4 + r;
        int col = m0 + wc + fn * 16 + l15;
        float v = acc[fm][fn][r] + bias[col];
        if (relu) v = fmaxf(v, 0.f);
        if constexpr (CBF) {
          ((u16*)C)[(size_t)row * M + col] = f2bf(v);
        } else {
          if (resid) v += resid[(size_t)row * M + col];
          ((float*)C)[(size_t)row * M + col] = v;
        }
      }
}

// ---------------- GEMM 64x64 (1 wave) ----------------
template <int CBF>
__global__ __launch_bounds__(64) void gemm64_kernel(const u16* __restrict__ A,
                                                    const u16* __restrict__ W,
                                                    const float* __restrict__ bias,
                                                    const float* __restrict__ resid,
                                                    void* __restrict__ C,
                                                    int N, int M, int K, int relu) {
  __shared__ u16 As[64 * 32];
  __shared__ u16 Ws[64 * 32];
  int lane = threadIdx.x;
  int l15 = lane & 15, lg = lane >> 4;
  int n0 = blockIdx.y * 64, m0 = blockIdx.x * 64;
  const u16* Ag = A + (size_t)(n0 + (lane >> 2)) * K + (lane & 3) * 8;
  const u16* Wg = W + (size_t)(m0 + (lane >> 2)) * K + (lane & 3) * 8;
  f32x4 acc[4][4] = {};
  for (int k0 = 0; k0 < K; k0 += 32) {
    __syncthreads();
#pragma unroll
    for (int i = 0; i < 4; ++i) {
      gload16(Ag + (size_t)(i * 16) * K + k0, &As[i * 512]);
      gload16(Wg + (size_t)(i * 16) * K + k0, &Ws[i * 512]);
    }
    __syncthreads();
    bf16x8 af[4], wf[4];
#pragma unroll
    for (int f = 0; f < 4; ++f) {
      af[f] = *(const bf16x8*)&As[(f * 16 + l15) * 32 + lg * 8];
      wf[f] = *(const bf16x8*)&Ws[(f * 16 + l15) * 32 + lg * 8];
    }
#pragma unroll
    for (int fm = 0; fm < 4; ++fm)
#pragma unroll
      for (int fn = 0; fn < 4; ++fn)
        acc[fm][fn] = __builtin_amdgcn_mfma_f32_16x16x32_bf16(af[fm], wf[fn], acc[fm][fn], 0, 0, 0);
  }
#pragma unroll
  for (int fm = 0; fm < 4; ++fm)
#pragma unroll
    for (int fn = 0; fn < 4; ++fn)
#pragma unroll
      for (int r = 0; r < 4; ++r) {
        int row = n0 + fm * 16 + lg * 4 + r;
        int col = m0 + fn * 16 + l15;
        float v = acc[fm][fn][r] + bias[col];
        if (relu) v = fmaxf(v, 0.f);
        if constexpr (CBF) {
          ((u16*)C)[(size_t)row * M + col] = f2bf(v);
        } else {
          if (resid) v += resid[(size_t)row * M + col];
          ((float*)C)[(size_t)row * M + col] = v;
        }
      }
}

// ---------------- LDS-staged split-K flash attention ----------------
// 8 waves (512 thr), Q=128/block. Per 64-key chunk: one cooperative 8KB
// coalesced stage (K[64][KP] + Vt[32][VP], padded), double-buffered with ONE
// raw s_barrier per chunk; next chunk's global load issues before compute so
// it flies under MFMA+softmax. Swapped QK^T (lane=query), exp2-domain
// softmax, deferred rescale. Writes unnormalized bf16 partials + f32 m/l.
#define KP 40   // K LDS row stride (u16): 80B -> 2-way banks on b128
#define VP 68   // V LDS row stride (u16): 136B, 8B-aligned, spread banks

__global__ __launch_bounds__(512) void attn_kernel(
    const u16* __restrict__ Q, const u16* __restrict__ Kp,
    const u16* __restrict__ Vt,
    int ldq, int ldk, int ldvt, int Sk, int nqt, int ksplit,
    int qB, int kB, int vB, const int* __restrict__ img, float scale,
    u16* __restrict__ opart, float* __restrict__ mlpart) {
  __shared__ u16 Ks[2][64 * KP];
  __shared__ u16 Vs[2][32 * VP];
  int tid = threadIdx.x, lane = tid & 63, w = tid >> 6;
  int l15 = lane & 15, lg = lane >> 4;
  int u_ = blockIdx.x;
  int wid = (u_ & 7) * (gridDim.x >> 3) + (u_ >> 3);  // XCD remap (grid%8==0)
  int ntile = gridDim.x / ksplit;
  int split = wid / ntile, tile = wid % ntile;
  int qt = tile % nqt, bh = tile / nqt, h = bh & 7, b = bh >> 3;
  int q_tile = qt * 128 + w * 16;

  const u16* Qb = Q + (size_t)b * qB + h * 32;
  const u16* Kb = Kp + (size_t)b * kB + h * 32;
  const u16* Vb = Vt + (size_t)(h * 32) * ldvt + b * vB;

  // admissible chunk range (contiguous: img_ids are sorted pairs)
  int c_lo = 0, c_cnt = Sk >> 6;
  if (img) {
    int qimg = img[q_tile >> 9];
    unsigned long long adm = 0;
#pragma unroll
    for (int j = 0; j < 8; ++j)
      if (img[j] == qimg) adm |= (0xFFull << (8 * j));
    c_lo = __ffsll((long long)adm) - 1;
    c_cnt = __popcll(adm);
  }
  int cbeg = c_lo + (c_cnt * split) / ksplit;
  int cend = c_lo + (c_cnt * (split + 1)) / ksplit;

  // staging map: tids 0..255 -> K rows (64 x 64B, 16B/thread);
  //              tids 256..511 -> V rows (32 x 128B, 16B/thread)
  int krow = tid >> 2, kcol = (tid & 3) * 8;
  int vrow = (tid & 255) >> 3, vcol = (tid & 7) * 8;
  bool isk = tid < 256;

  bf16x8 qf;
  {
    bf16x8 qr = *(const bf16x8*)(Qb + (size_t)(q_tile + l15) * ldq + lg * 8);
#pragma unroll
    for (int i = 0; i < 8; ++i) qf[i] = (short)f2bf(bf2f((u16)qr[i]) * scale);
  }

  float m_ = -1e30f, l_ = 0.f;
  f32x4 o0 = {}, o1 = {};

  auto gsrc = [&](int cc) -> const u16* {
    return isk ? Kb + (size_t)((cc << 6) + krow) * ldk + kcol
               : Vb + (size_t)vrow * ldvt + (cc << 6) + vcol;
  };
  // prologue load
  bf16x8 r = *(const bf16x8*)gsrc(cbeg);

  for (int c = cbeg; c < cend; ++c) {
    int p = (c - cbeg) & 1;
    u16* dst = isk ? &Ks[p][krow * KP + kcol] : &Vs[p][vrow * VP + vcol];
    *(bf16x8*)dst = r;
    asm volatile("s_waitcnt lgkmcnt(0)" ::: "memory");
    int cn = (c + 1 < cend) ? c + 1 : cend - 1;
    r = *(const bf16x8*)gsrc(cn);   // flies under compute below
    __builtin_amdgcn_s_barrier();
    asm volatile("" ::: "memory");
    // ---- QK^T (swapped): 4 tiles of 16 keys from LDS ----
    f32x4 z = {};
    f32x4 st[4];
#pragma unroll
    for (int t = 0; t < 4; ++t) {
      bf16x8 kf = *(const bf16x8*)&Ks[p][(t * 16 + l15) * KP + lg * 8];
      st[t] = __builtin_amdgcn_mfma_f32_16x16x32_bf16(kf, qf, z, 0, 0, 0);
    }
    // ---- online softmax (exp2 domain, deferred rescale) ----
    float a0 = fmaxf(fmaxf(st[0][0], st[0][1]), fmaxf(st[0][2], st[0][3]));
    float a1 = fmaxf(fmaxf(st[1][0], st[1][1]), fmaxf(st[1][2], st[1][3]));
    float a2 = fmaxf(fmaxf(st[2][0], st[2][1]), fmaxf(st[2][2], st[2][3]));
    float a3 = fmaxf(fmaxf(st[3][0], st[3][1]), fmaxf(st[3][2], st[3][3]));
    float cm = fmaxf(fmaxf(a0, a1), fmaxf(a2, a3));
    cm = fmaxf(cm, __shfl_xor(cm, 16));
    cm = fmaxf(cm, __shfl_xor(cm, 32));
    bool need = __any(cm > m_);
    float mn = fmaxf(m_, cm);
    float pv[4][4];
    float r4[4];
#pragma unroll
    for (int t = 0; t < 4; ++t) {
      pv[t][0] = __builtin_exp2f(st[t][0] - mn);
      pv[t][1] = __builtin_exp2f(st[t][1] - mn);
      pv[t][2] = __builtin_exp2f(st[t][2] - mn);
      pv[t][3] = __builtin_exp2f(st[t][3] - mn);
      r4[t] = (pv[t][0] + pv[t][1]) + (pv[t][2] + pv[t][3]);
    }
    float rs = (r4[0] + r4[1]) + (r4[2] + r4[3]);
    rs += __shfl_xor(rs, 16);
    rs += __shfl_xor(rs, 32);
    if (need) {
      float sf = __builtin_exp2f(m_ - mn);
      m_ = mn;
#pragma unroll
      for (int q = 0; q < 4; ++q) {
        float s4 = __shfl(sf, lg * 4 + q);
        o0[q] *= s4;
        o1[q] *= s4;
      }
      l_ = l_ * sf + rs;
    } else {
      l_ += rs;
    }
    // ---- PV from LDS V (transposed) ----
#pragma unroll
    for (int t = 0; t < 4; ++t) {
      bf16x4 pa;
      pa[0] = (short)f2bf(pv[t][0]); pa[1] = (short)f2bf(pv[t][1]);
      pa[2] = (short)f2bf(pv[t][2]); pa[3] = (short)f2bf(pv[t][3]);
      bf16x4 v0 = *(const bf16x4*)&Vs[p][l15 * VP + t * 16 + lg * 4];
      bf16x4 v1 = *(const bf16x4*)&Vs[p][(16 + l15) * VP + t * 16 + lg * 4];
      o0 = __builtin_amdgcn_mfma_f32_16x16x16bf16_1k(pa, v0, o0, 0, 0, 0);
      o1 = __builtin_amdgcn_mfma_f32_16x16x16bf16_1k(pa, v1, o1, 0, 0, 0);
    }
  }

  // ---- write partials (blk = tile*ksplit + split; 128q x 32d per blk) ----
  int blk = tile * ksplit + split;
  u16* op = opart + (size_t)blk * 4096;
#pragma unroll
  for (int q = 0; q < 4; ++q) {
    int ql = w * 16 + lg * 4 + q;
    op[ql * 32 + l15] = f2bf(o0[q]);
    op[ql * 32 + 16 + l15] = f2bf(o1[q]);
  }
  if (lg == 0) {
    float* ml = mlpart + (size_t)blk * 256;
    ml[w * 16 + l15] = m_;
    ml[128 + w * 16 + l15] = l_;
  }
}

// ---------------- combine partials -> bf16 output [tok][256] ----------------
template <int KS>
__global__ __launch_bounds__(256) void attn_combine(const u16* __restrict__ opart,
                                                    const float* __restrict__ mlpart,
                                                    u16* __restrict__ O,
                                                    int nqt, int SqB) {
  int tile = blockIdx.x;
  int qt = tile % nqt, bh = tile / nqt, h = bh & 7, b = bh >> 3;
  int t = threadIdx.x;
  int q = t >> 1, d0 = (t & 1) * 16;
  float m[KS], l[KS];
#pragma unroll
  for (int s = 0; s < KS; ++s) {
    const float* ml = mlpart + (size_t)(tile * KS + s) * 256;
    m[s] = ml[q];
    l[s] = ml[128 + q];
  }
  float M = m[0];
#pragma unroll
  for (int s = 1; s < KS; ++s) M = fmaxf(M, m[s]);
  float wgt[KS];
  float L = 0.f;
#pragma unroll
  for (int s = 0; s < KS; ++s) {
    wgt[s] = __builtin_exp2f(m[s] - M);
    L += l[s] * wgt[s];
  }
  float inv = 1.f / L;
  float acc[16] = {};
#pragma unroll
  for (int s = 0; s < KS; ++s) {
    const u16* op = opart + (size_t)(tile * KS + s) * 4096 + q * 32 + d0;
    bf16x8 v0 = *(const bf16x8*)op;
    bf16x8 v1 = *(const bf16x8*)(op + 8);
#pragma unroll
    for (int j = 0; j < 8; ++j) {
      acc[j] += bf2f((u16)v0[j]) * wgt[s];
      acc[8 + j] += bf2f((u16)v1[j]) * wgt[s];
    }
  }
  u16* out = O + ((size_t)(b * SqB + qt * 128 + q)) * 256 + h * 32 + d0;
  bf16x8 w0, w1;
#pragma unroll
  for (int j = 0; j < 8; ++j) {
    w0[j] = (short)f2bf(acc[j] * inv);
    w1[j] = (short)f2bf(acc[8 + j] * inv);
  }
  *(bf16x8*)out = w0;
  *(bf16x8*)(out + 8) = w1;
}

// ---------------- orchestration ----------------
extern "C" void kernel_launch(void* const* d_in, const int* in_sizes, int n_in,
                              void* d_out, int out_size, void* d_ws, size_t ws_size,
                              hipStream_t stream) {
  const float* curr       = (const float*)d_in[0];
  const float* memory     = (const float*)d_in[1];
  const float* curr_pos   = (const float*)d_in[2];
  const float* memory_pos = (const float*)d_in[3];
  const int*   img_ids    = (const int*)d_in[4];
  const float* sa_w_in  = (const float*)d_in[5];
  const float* sa_b_in  = (const float*)d_in[6];
  const float* sa_w_out = (const float*)d_in[7];
  const float* sa_b_out = (const float*)d_in[8];
  const float* co_w_in  = (const float*)d_in[9];
  const float* co_b_in  = (const float*)d_in[10];
  const float* co_w_out = (const float*)d_in[11];
  const float* co_b_out = (const float*)d_in[12];
  const float* ca_w_in  = (const float*)d_in[13];
  const float* ca_b_in  = (const float*)d_in[14];
  const float* ca_w_out = (const float*)d_in[15];
  const float* ca_b_out = (const float*)d_in[16];
  const float* obj_emb  = (const float*)d_in[17];
  const float* obj_scale= (const float*)d_in[18];
  const float* n1_g = (const float*)d_in[19];
  const float* n1_b = (const float*)d_in[20];
  const float* n2_g = (const float*)d_in[21];
  const float* n2_b = (const float*)d_in[22];
  const float* n3_g = (const float*)d_in[23];
  const float* n3_b = (const float*)d_in[24];
  const float* w1 = (const float*)d_in[25];
  const float* b1 = (const float*)d_in[26];
  const float* w2 = (const float*)d_in[27];
  const float* b2 = (const float*)d_in[28];
  const float* norm_g = (const float*)d_in[29];
  const float* norm_b = (const float*)d_in[30];
  float* out = (float*)d_out;

  char* p = (char*)d_ws;
  float* x    = (float*)p;  p += (size_t)NTOK * DMODEL * 4;
  u16* t2b    = (u16*)p;    p += (size_t)NTOK * DMODEL * 2;
  u16* qkvb   = (u16*)p;    p += (size_t)NTOK * 768 * 2;
  u16* qproj  = (u16*)p;    p += (size_t)NTOK * DMODEL * 2;
  u16* attb   = (u16*)p;    p += (size_t)NTOK * DMODEL * 2;
  u16* memk   = (u16*)p;    p += (size_t)NMEM * DMODEL * 2;
  u16* memv   = (u16*)p;    p += (size_t)NMEM * DMODEL * 2;
  u16* kbufb  = (u16*)p;    p += (size_t)NMEM * DMODEL * 2;
  u16* vbufb  = (u16*)p;    p += (size_t)NMEM * DMODEL * 2;  // hbuf alias in MLP
  u16* vtca   = (u16*)p;    p += (size_t)NMEM * DMODEL * 2;
  u16* vtx    = (u16*)p;    p += (size_t)NTOK * DMODEL * 2;
  u16* wbf    = (u16*)p;    p += (size_t)3670016 * 2;
  u16* hbufb  = vbufb;
  // partials: SA/CO alias kbufb (dead there); CA alias vbufb (dead post-transpose)
  // max 1024 blocks * 4096 u16 = 8MB partials + 1MB ml, both fit the 16MB bufs
  u16* opart1   = kbufb;
  float* mlp1   = (float*)(kbufb + 1024 * 4096);
  u16* opart2   = vbufb;
  float* mlp2   = (float*)(vbufb + 1024 * 4096);

  const float scale = 0.17677669529663687f * 1.4426950408889634f;  // /sqrt(32)*log2e

  WArgs wa;
  const float* sp[8] = {sa_w_in, sa_w_out, co_w_in, co_w_out, ca_w_in, ca_w_out, w1, w2};
  int sz[8] = {393216, 131072, 393216, 131072, 393216, 131072, 1048576, 1048576};
  {
    int off = 0;
    for (int j = 0; j < 8; ++j) { wa.src[j] = sp[j]; wa.off[j] = off; wa.n[j] = sz[j]; off += sz[j]; }
  }
  const int O_SA_IN = 0, O_SA_OUT = 393216, O_CO_IN = 524288, O_CO_OUT = 917504;
  const int O_CA_IN = 1048576, O_CA_OUT = 1441792, O_W1 = 1572864, O_W2 = 2621440;

  wcast_kernel<<<512, 256, 0, stream>>>(wa, wbf);
  memprep_kernel<<<2048, 256, 0, stream>>>(memory, memory_pos, memk, memv, NMEM * DMODEL / 8);
  add_kernel<<<1024, 256, 0, stream>>>(curr, curr_pos, 0.1f, x, NTOK * DMODEL / 4);

  for (int l = 0; l < 2; ++l) {
    const u16* w_sa_in  = wbf + O_SA_IN  + l * 196608;
    const u16* w_sa_out = wbf + O_SA_OUT + l * 65536;
    const u16* w_co_in  = wbf + O_CO_IN  + l * 196608;
    const u16* w_co_out = wbf + O_CO_OUT + l * 65536;
    const u16* w_ca_in  = wbf + O_CA_IN  + l * 196608;
    const u16* w_ca_out = wbf + O_CA_OUT + l * 65536;
    const u16* w_1      = wbf + O_W1     + l * 524288;
    const u16* w_2      = wbf + O_W2     + l * 524288;

    // ---- self-attention (ntile=256 [Q=128], ksplit=2 -> grid 512) ----
    ln_kernel<1><<<NTOK, 256, 0, stream>>>(x, n1_g + l * 256, n1_b + l * 256, t2b);
    gemm64_kernel<1><<<dim3(12, 64), 64, 0, stream>>>(t2b, w_sa_in, sa_b_in + l * 768,
                                                      nullptr, qkvb, NTOK, 768, 256, 0);
    transpose_v<<<dim3(64, 8), 256, 0, stream>>>(qkvb, 768, 512, vtx, NTOK);
    attn_kernel<<<512, 512, 0, stream>>>(qkvb, qkvb + 256, vtx,
                                         768, 768, 4096, 512, 4, 2,
                                         512 * 768, 512 * 768, 512, nullptr, scale,
                                         opart1, mlp1);
    attn_combine<2><<<256, 256, 0, stream>>>(opart1, mlp1, attb, 4, 512);
    gemm64_kernel<0><<<dim3(4, 64), 64, 0, stream>>>(attb, w_sa_out, sa_b_out + l * 256,
                                                     x, x, NTOK, 256, 256, 0);
    // ---- cross-object attention (ntile=256, ksplit=4 -> grid 1024, mask) ----
    enh_kernel<<<1024, 256, 0, stream>>>(x, obj_emb + l * 8 * 256, obj_scale + l,
                                         t2b, NTOK * DMODEL / 4);
    gemm64_kernel<1><<<dim3(12, 64), 64, 0, stream>>>(t2b, w_co_in, co_b_in + l * 768,
                                                      nullptr, qkvb, NTOK, 768, 256, 0);
    transpose_v<<<dim3(64, 8), 256, 0, stream>>>(qkvb, 768, 512, vtx, NTOK);
    attn_kernel<<<1024, 512, 0, stream>>>(qkvb, qkvb + 256, vtx,
                                          768, 768, 4096, 4096, 32, 4,
                                          0, 0, 0, img_ids, scale,
                                          opart1, mlp1);
    attn_combine<4><<<256, 256, 0, stream>>>(opart1, mlp1, attb, 32, 4096);
    gemm64_kernel<0><<<dim3(4, 64), 64, 0, stream>>>(attb, w_co_out, co_b_out + l * 256,
                                                     x, x, NTOK, 256, 256, 0);
    // ---- cross-attention to memory (ntile=256, ksplit=4 -> grid 1024) ----
    ln_kernel<1><<<NTOK, 256, 0, stream>>>(x, n2_g + l * 256, n2_b + l * 256, t2b);
    gemm64_kernel<1><<<dim3(4, 64), 64, 0, stream>>>(t2b, w_ca_in, ca_b_in + l * 768,
                                                     nullptr, qproj, NTOK, 256, 256, 0);
    gemm128_kernel<1><<<dim3(2, 256), 256, 0, stream>>>(memk, w_ca_in + 65536,
                                                        ca_b_in + l * 768 + 256, nullptr,
                                                        kbufb, NMEM, 256, 256, 0);
    gemm128_kernel<1><<<dim3(2, 256), 256, 0, stream>>>(memv, w_ca_in + 131072,
                                                        ca_b_in + l * 768 + 512, nullptr,
                                                        vbufb, NMEM, 256, 256, 0);
    transpose_v<<<dim3(512, 8), 256, 0, stream>>>(vbufb, 256, 0, vtca, NMEM);
    attn_kernel<<<1024, 512, 0, stream>>>(qproj, kbufb, vtca,
                                          256, 256, 32768, 4096, 4, 4,
                                          512 * 256, 4096 * 256, 4096, nullptr, scale,
                                          opart2, mlp2);
    attn_combine<4><<<256, 256, 0, stream>>>(opart2, mlp2, attb, 4, 512);
    gemm64_kernel<0><<<dim3(4, 64), 64, 0, stream>>>(attb, w_ca_out, ca_b_out + l * 256,
                                                     x, x, NTOK, 256, 256, 0);
    // ---- MLP ----
    ln_kernel<1><<<NTOK, 256, 0, stream>>>(x, n3_g + l * 256, n3_b + l * 256, t2b);
    gemm128_kernel<1><<<dim3(16, 32), 256, 0, stream>>>(t2b, w_1, b1 + l * 2048, nullptr,
                                                        hbufb, NTOK, 2048, 256, 1);
    gemm64_kernel<0><<<dim3(4, 64), 64, 0, stream>>>(hbufb, w_2, b2 + l * 256,
                                                     x, x, NTOK, 256, 2048, 0);
  }
  ln_kernel<0><<<NTOK, 256, 0, stream>>>(x, norm_g, norm_b, out);
}